// Round 1
// baseline (169.516 us; speedup 1.0000x reference)
//
#include <hip/hip_runtime.h>
#include <math.h>

// ---------- types ----------
typedef __bf16 bf16_t;
typedef __bf16 bf16x8 __attribute__((ext_vector_type(8)));
typedef __bf16 bf16x4 __attribute__((ext_vector_type(4)));
typedef float  f32x4  __attribute__((ext_vector_type(4)));

#define MFMA16(a, b, c) __builtin_amdgcn_mfma_f32_16x16x32_bf16((a), (b), (c), 0, 0, 0)

// B=2, N=M=2048, QUERY_DIM=CONTEXT_DIM=1024, HEADS=8, DIM_HEAD=64, INNER=512
#define INNER   512
#define DHEAD   64
// SCALE * log2(e): Q pre-scaled so softmax runs in exp2 domain
#define QSCALE  0.18033688f

// direct HBM -> LDS, 16 B per lane; LDS dest = wave-uniform base + lane*16
__device__ __forceinline__ void g2l(const bf16_t* g, bf16_t* l) {
  __builtin_amdgcn_global_load_lds(
      (const __attribute__((address_space(1))) unsigned int*)g,
      (__attribute__((address_space(3))) unsigned int*)l, 16, 0, 0);
}

// ---------- weight transpose+convert only (x/ctx convert fused into GEMM) ----------
__global__ __launch_bounds__(256) void pre_w_k(const float* __restrict__ Wq,
                                               const float* __restrict__ Wk,
                                               const float* __restrict__ Wv,
                                               const float* __restrict__ Wo,
                                               bf16_t* __restrict__ WqT,
                                               bf16_t* __restrict__ WkT,
                                               bf16_t* __restrict__ WvT,
                                               bf16_t* __restrict__ WoT) {
  __shared__ float tile[64][65];
  int t = blockIdx.x;               // 0..511, 4 matrices x 128 tiles
  int z = t >> 7, bid = t & 127;
  const float* W; bf16_t* WT; int K, N;
  if (z == 0)      { W = Wq; WT = WqT; K = 1024; N = 512; }
  else if (z == 1) { W = Wk; WT = WkT; K = 1024; N = 512; }
  else if (z == 2) { W = Wv; WT = WvT; K = 1024; N = 512; }
  else             { W = Wo; WT = WoT; K = 512;  N = 1024; }
  int tK = K >> 6;
  int kt = bid % tK, nt = bid / tK;
  int k0 = kt << 6, n0 = nt << 6;
  for (int idx = threadIdx.x; idx < 4096; idx += 256) {
    int r = idx >> 6, c = idx & 63;
    tile[r][c] = W[(size_t)(k0 + r) * N + n0 + c];
  }
  __syncthreads();
  for (int idx = threadIdx.x; idx < 4096; idx += 256) {
    int r = idx >> 6, c = idx & 63;
    WT[(size_t)(n0 + r) * K + k0 + c] = (bf16_t)tile[c][r];
  }
}

// ---------- BMx128 GEMM, BK=64, double-buffered staging with early issue ----------
// LDS tiles BMx64 / 128x64 bf16 (128-B rows), XOR-swizzled 16-B chunks:
// phys = log ^ (row&7).
// B operand: global_load_lds from pre-swizzled global address (bf16).
// A operand: if AF32, reg-staged from fp32 (load early -> MFMA -> cvt+ds_write late,
//            T14 issue-early/write-late split), swizzled ds_write_b128.
// One barrier per iteration.
// mode 0: bf16 out * scale; mode 1: f32 out + bias; mode 2: scatter to Vt.
template<int BM, bool AF32>
__device__ __forceinline__ void gemm_core(const void* __restrict__ Ap,
                                          const bf16_t* __restrict__ Bt,
                                          int K, int N, int row0, int n0,
                                          int mode, float scale,
                                          bf16_t* __restrict__ Cb,
                                          float* __restrict__ Cf,
                                          const float* __restrict__ bias) {
  constexpr int MI = BM / 32;              // A frag-rows per wave == A staging steps
  __shared__ bf16_t As[2 * BM * 64];       // 16/32 KB
  __shared__ bf16_t Bs[2 * 128 * 64];      // 32 KB
  const int tid = threadIdx.x;
  const int w = tid >> 6, lane = tid & 63, quad = lane >> 4, l16 = lane & 15;

  // staging geometry: wave w covers rows [w*BM/4, w*BM/4 + BM/4) of A,
  // [w*32, w*32+32) of B; per step p: rows +p*8+(lane>>3), 16B chunk per lane.
  // logical chunk = (lane&7)^(lane>>3) so that LDS phys chunk (lane&7) holds
  // log ^ (row&7).
  const int sr8  = lane >> 3;                    // 0..7
  const int slog = ((lane & 7) ^ sr8) << 3;      // logical col (elems)
  const float*  gaF = nullptr;
  const bf16_t* gaB = nullptr;
  {
    size_t aoff = (size_t)(row0 + w * (BM / 4) + sr8) * K + slog;
    if constexpr (AF32) gaF = (const float*)Ap + aoff;
    else                gaB = (const bf16_t*)Ap + aoff;
  }
  const bf16_t* gb = Bt + (size_t)(n0 + w * 32 + sr8) * K + slog;
  bf16_t* lA = As + w * (BM / 4) * 64;           // + buf*BM*64 + p*512
  bf16_t* lB = Bs + w * 2048;                    // + buf*8192  + p*512

  f32x4 acc[MI][4];
#pragma unroll
  for (int i = 0; i < MI; ++i)
#pragma unroll
    for (int j = 0; j < 4; ++j) acc[i][j] = f32x4{0.f, 0.f, 0.f, 0.f};

  const int mrow = (w & 1) * (BM / 2), ncol = (w >> 1) << 6;
  const int KT = K >> 6;

  // prologue: tile 0 -> buf 0
  if constexpr (AF32) {
#pragma unroll
    for (int p = 0; p < MI; ++p) {
      const float* s = gaF + (size_t)(p * 8) * K;
      f32x4 f0 = *(const f32x4*)s;
      f32x4 f1 = *(const f32x4*)(s + 4);
      bf16x8 h;
#pragma unroll
      for (int e = 0; e < 4; ++e) { h[e] = (bf16_t)f0[e]; h[4 + e] = (bf16_t)f1[e]; }
      *(bf16x8*)&lA[p * 512 + lane * 8] = h;
    }
  } else {
#pragma unroll
    for (int p = 0; p < MI; ++p)
      g2l(gaB + (size_t)(p * 8) * K, lA + p * 512);
  }
#pragma unroll
  for (int p = 0; p < 4; ++p)
    g2l(gb + (size_t)(p * 8) * K, lB + p * 512);

  for (int kc = 0; kc < KT; ++kc) {
    const int curA = (kc & 1) * (BM * 64), nxtA = ((kc + 1) & 1) * (BM * 64);
    const int curB = (kc & 1) * 8192,      nxtB = ((kc + 1) & 1) * 8192;
    __syncthreads();              // drains tile-kc loads/writes; publishes buf[cur]
    f32x4 fpre[2 * MI];
    const bool pf = (kc + 1 < KT);
    if (pf) {                     // issue tile kc+1 early; MFMA hides flight
      const int k0 = (kc + 1) * 64;
#pragma unroll
      for (int p = 0; p < 4; ++p)
        g2l(gb + (size_t)(p * 8) * K + k0, lB + nxtB + p * 512);
      if constexpr (AF32) {
#pragma unroll
        for (int p = 0; p < MI; ++p) {
          const float* s = gaF + (size_t)(p * 8) * K + k0;
          fpre[2 * p]     = *(const f32x4*)s;
          fpre[2 * p + 1] = *(const f32x4*)(s + 4);
        }
      } else {
#pragma unroll
        for (int p = 0; p < MI; ++p)
          g2l(gaB + (size_t)(p * 8) * K + k0, lA + nxtA + p * 512);
      }
    }
#pragma unroll
    for (int ks = 0; ks < 2; ++ks) {
      const int phys = ((ks * 4 + quad) ^ (l16 & 7)) << 3;
      bf16x8 af[MI], bfr[4];
#pragma unroll
      for (int i = 0; i < MI; ++i)
        af[i] = *(const bf16x8*)&As[curA + (mrow + i * 16 + l16) * 64 + phys];
#pragma unroll
      for (int j = 0; j < 4; ++j)
        bfr[j] = *(const bf16x8*)&Bs[curB + (ncol + j * 16 + l16) * 64 + phys];
#pragma unroll
      for (int i = 0; i < MI; ++i)
#pragma unroll
        for (int j = 0; j < 4; ++j)
          acc[i][j] = MFMA16(af[i], bfr[j], acc[i][j]);
    }
    if (pf) {
      if constexpr (AF32) {       // write-late: cvt + swizzled ds_write into nxt
#pragma unroll
        for (int p = 0; p < MI; ++p) {
          bf16x8 h;
#pragma unroll
          for (int e = 0; e < 4; ++e) {
            h[e]     = (bf16_t)fpre[2 * p][e];
            h[4 + e] = (bf16_t)fpre[2 * p + 1][e];
          }
          *(bf16x8*)&lA[nxtA + p * 512 + lane * 8] = h;
        }
      }
    }
  }

  // epilogue: C/D layout col=l16, row=quad*4+reg
#pragma unroll
  for (int i = 0; i < MI; ++i) {
    int row = row0 + mrow + i * 16 + quad * 4;
#pragma unroll
    for (int j = 0; j < 4; ++j) {
      int col = n0 + ncol + j * 16 + l16;
      if (mode == 2) {
        // scatter to Vt[bh=b*8+h][d][key]: row -> (b,key), col -> (h,d)
        int bb = row >> 11, key = row & 2047;
        int hh = col >> 6,  d   = col & 63;
        bf16x4 v = { (bf16_t)acc[i][j][0], (bf16_t)acc[i][j][1],
                     (bf16_t)acc[i][j][2], (bf16_t)acc[i][j][3] };
        *(bf16x4*)&Cb[((size_t)((bb * 8 + hh) * 64 + d)) * 2048 + key] = v;
      } else {
#pragma unroll
        for (int r = 0; r < 4; ++r) {
          if (mode == 1) Cf[(size_t)(row + r) * N + col] = acc[i][j][r] + bias[col];
          else           Cb[(size_t)(row + r) * N + col] = (bf16_t)(acc[i][j][r] * scale);
        }
      }
    }
  }
}

__global__ __launch_bounds__(256, 2) void gemm_qkv_k(const float* __restrict__ x,
                                                     const float* __restrict__ ctx,
                                                     const bf16_t* __restrict__ WqT,
                                                     const bf16_t* __restrict__ WkT,
                                                     const bf16_t* __restrict__ WvT,
                                                     bf16_t* __restrict__ Qb,
                                                     bf16_t* __restrict__ Kb,
                                                     bf16_t* __restrict__ Vt) {
  int z = blockIdx.z;
  const float* A   = (z == 0) ? x   : ctx;
  const bf16_t* Bt = (z == 0) ? WqT : (z == 1) ? WkT : WvT;
  bf16_t* C        = (z == 0) ? Qb  : (z == 1) ? Kb  : Vt;
  int mode         = (z == 2) ? 2 : 0;
  float scale      = (z == 0) ? QSCALE : 1.0f;
  gemm_core<128, true>(A, Bt, 1024, 512, blockIdx.y * 128, blockIdx.x * 128,
                       mode, scale, C, nullptr, nullptr);
}

// 64x128 tile: 512 blocks, 48 KB LDS -> 3 blocks/CU, barrier drain overlapped
__global__ __launch_bounds__(256, 2) void gemm_out_k(const bf16_t* __restrict__ AO,
                                                     const bf16_t* __restrict__ WoT,
                                                     const float* __restrict__ bo,
                                                     float* __restrict__ out) {
  gemm_core<64, false>(AO, WoT, 512, 1024, blockIdx.y * 64, blockIdx.x * 128,
                       1, 1.0f, nullptr, out, bo);
}

// ---------- flash attention: transposed-S, pipelined staging (unchanged) ----------
__global__ __launch_bounds__(256, 2) void attn_k(const bf16_t* __restrict__ Qb,
                                                 const bf16_t* __restrict__ Kb,
                                                 const bf16_t* __restrict__ Vt,
                                                 bf16_t* __restrict__ AO) {
  const int tid = threadIdx.x;
  const int w = tid >> 6, lane = tid & 63, quad = lane >> 4, l16 = lane & 15;
  const int qt = blockIdx.x;        // 0..31
  const int bh = blockIdx.y;        // 0..15
  const int b = bh >> 3, h = bh & 7;

  __shared__ bf16_t Ks[2 * 128 * 64];  // [buf][key][d] rows 128 B, swizzle r&7
  __shared__ bf16_t Vs[64 * 128];      // [d][key]      rows 256 B, swizzle r&15
  __shared__ bf16_t Ps[64 * 136];      // [q][key]      padded, wave-private rows

  const int qrow = b * 2048 + qt * 64 + w * 16 + l16;
  const bf16_t* qptr = Qb + (size_t)qrow * INNER + h * DHEAD;
  bf16x8 bq[2];
  bq[0] = *(const bf16x8*)(qptr + quad * 8);
  bq[1] = *(const bf16x8*)(qptr + 32 + quad * 8);

  f32x4 o[4];
#pragma unroll
  for (int dt = 0; dt < 4; ++dt) o[dt] = f32x4{0.f, 0.f, 0.f, 0.f};
  float m_s = -__builtin_inff(), l_s = 0.f;

  const bf16_t* kbase  = Kb + ((size_t)b * 2048) * INNER + h * DHEAD;
  const bf16_t* vtbase = Vt + ((size_t)bh * 64) * 2048;

  const int krow = lane >> 3;
  const int kcol = ((lane & 7) ^ (lane >> 3)) << 3;
  const int vrow = lane >> 4;

#pragma unroll
  for (int p = 0; p < 4; ++p)
    g2l(kbase + (size_t)(w * 32 + p * 8 + krow) * INNER + kcol,
        &Ks[w * 2048 + p * 512]);

  for (int kt = 0; kt < 16; ++kt) {
    const int cur = (kt & 1) * 8192, nxt = ((kt + 1) & 1) * 8192;
    __syncthreads();
    if (kt < 16 - 1) {
#pragma unroll
      for (int p = 0; p < 4; ++p)
        g2l(kbase + (size_t)((kt + 1) * 128 + w * 32 + p * 8 + krow) * INNER + kcol,
            &Ks[nxt + w * 2048 + p * 512]);
    }
#pragma unroll
    for (int p = 0; p < 4; ++p) {
      int vlog = ((lane & 15) ^ ((p * 4 + vrow) & 15)) << 3;
      g2l(vtbase + (size_t)(w * 16 + p * 4 + vrow) * 2048 + kt * 128 + vlog,
          &Vs[w * 2048 + p * 512]);
    }

    f32x4 s[8];
#pragma unroll
    for (int jt = 0; jt < 8; ++jt) s[jt] = f32x4{0.f, 0.f, 0.f, 0.f};
#pragma unroll
    for (int jt = 0; jt < 8; ++jt) {
#pragma unroll
      for (int ks = 0; ks < 2; ++ks) {
        int phys = ((ks * 4 + quad) ^ (l16 & 7)) << 3;
        bf16x8 ak = *(const bf16x8*)&Ks[cur + (jt * 16 + l16) * 64 + phys];
        s[jt] = MFMA16(ak, bq[ks], s[jt]);
      }
    }

    float mx = -__builtin_inff();
#pragma unroll
    for (int jt = 0; jt < 8; ++jt) {
      float a = fmaxf(fmaxf(s[jt][0], s[jt][1]), fmaxf(s[jt][2], s[jt][3]));
      mx = fmaxf(mx, a);
    }
    mx = fmaxf(mx, __shfl_xor(mx, 16, 64));
    mx = fmaxf(mx, __shfl_xor(mx, 32, 64));
    float mnew = fmaxf(m_s, mx);
    float alpha = __builtin_amdgcn_exp2f(m_s - mnew);
    float rs = 0.f;
#pragma unroll
    for (int jt = 0; jt < 8; ++jt) {
#pragma unroll
      for (int r = 0; r < 4; ++r) {
        float p = __builtin_amdgcn_exp2f(s[jt][r] - mnew);
        s[jt][r] = p;
        rs += p;
      }
    }
    rs += __shfl_xor(rs, 16, 64);
    rs += __shfl_xor(rs, 32, 64);
    l_s = l_s * alpha + rs;
    m_s = mnew;
#pragma unroll
    for (int dt = 0; dt < 4; ++dt) o[dt] *= alpha;

#pragma unroll
    for (int jt = 0; jt < 8; ++jt) {
      bf16x4 pk = { (bf16_t)s[jt][0], (bf16_t)s[jt][1],
                    (bf16_t)s[jt][2], (bf16_t)s[jt][3] };
      *(bf16x4*)&Ps[(w * 16 + l16) * 136 + jt * 16 + quad * 4] = pk;
    }

    __syncthreads();

#pragma unroll
    for (int kc = 0; kc < 4; ++kc) {
      bf16x8 bp = *(const bf16x8*)&Ps[(w * 16 + l16) * 136 + kc * 32 + quad * 8];
#pragma unroll
      for (int dt = 0; dt < 4; ++dt) {
        int phys = ((kc * 4 + quad) ^ l16) << 3;
        bf16x8 av = *(const bf16x8*)&Vs[(dt * 16 + l16) * 128 + phys];
        o[dt] = MFMA16(av, bp, o[dt]);
      }
    }
  }

  float inv = 1.0f / l_s;
#pragma unroll
  for (int dt = 0; dt < 4; ++dt) {
    bf16x4 ov = { (bf16_t)(o[dt][0] * inv), (bf16_t)(o[dt][1] * inv),
                  (bf16_t)(o[dt][2] * inv), (bf16_t)(o[dt][3] * inv) };
    *(bf16x4*)&Ps[(w * 16 + l16) * 136 + dt * 16 + quad * 4] = ov;
  }
  __syncthreads();
  {
    int sr = tid >> 2, sc = (tid & 3) << 4;
    int4 r0 = *(const int4*)&Ps[sr * 136 + sc];
    int4 r1 = *(const int4*)&Ps[sr * 136 + sc + 8];
    bf16_t* aout = AO + ((size_t)(b * 2048 + qt * 64 + sr)) * INNER + h * DHEAD + sc;
    *(int4*)aout       = r0;
    *(int4*)(aout + 8) = r1;
  }
}

// ---------- launch ----------
extern "C" void kernel_launch(void* const* d_in, const int* in_sizes, int n_in,
                              void* d_out, int out_size, void* d_ws, size_t ws_size,
                              hipStream_t stream) {
  const float* x   = (const float*)d_in[0];
  const float* ctx = (const float*)d_in[1];
  const float* Wq  = (const float*)d_in[2];
  const float* Wk  = (const float*)d_in[3];
  const float* Wv  = (const float*)d_in[4];
  const float* Wo  = (const float*)d_in[5];
  const float* bo  = (const float*)d_in[6];
  float* out = (float*)d_out;

  char* ws = (char*)d_ws;
  const size_t MB = 1048576;
  bf16_t* WqT = (bf16_t*)(ws + 0 * MB);    //  1 MB  [512][1024]
  bf16_t* WkT = (bf16_t*)(ws + 1 * MB);    //  1 MB
  bf16_t* WvT = (bf16_t*)(ws + 2 * MB);    //  1 MB
  bf16_t* WoT = (bf16_t*)(ws + 3 * MB);    //  1 MB  [1024][512]
  bf16_t* Qb  = (bf16_t*)(ws + 4 * MB);    //  4 MB  [4096][512] (pre-scaled)
  bf16_t* Kb  = (bf16_t*)(ws + 8 * MB);    //  4 MB  [4096][512]
  bf16_t* Vt  = (bf16_t*)(ws + 12 * MB);   //  4 MB  [16][64][2048]
  bf16_t* AO  = (bf16_t*)(ws + 16 * MB);   //  4 MB  [4096][512]

  pre_w_k<<<512, 256, 0, stream>>>(Wq, Wk, Wv, Wo, WqT, WkT, WvT, WoT);
  gemm_qkv_k<<<dim3(4, 32, 3), 256, 0, stream>>>(x, ctx, WqT, WkT, WvT, Qb, Kb, Vt);
  attn_k<<<dim3(32, 16), 256, 0, stream>>>(Qb, Kb, Vt, AO);
  gemm_out_k<<<dim3(8, 64), 256, 0, stream>>>(AO, WoT, bo, out);
}